// Round 1
// baseline (407.368 us; speedup 1.0000x reference)
//
#include <hip/hip_runtime.h>

#define H 1024
#define LSEQ 2048
#define BATCH 16
#define M_TOT 32768          // B*L
#define KDIM 2048            // 2H
#define NEG_INF_F (-10000000000.0f)

typedef _Float16 f16;
typedef f16 f16x4 __attribute__((ext_vector_type(4)));
typedef f16 f16x8 __attribute__((ext_vector_type(8)));
typedef float f32x4 __attribute__((ext_vector_type(4)));

// ---------------- ws layout ----------------
// [0          , 4MB)          : we16  f16[1024][2048]   W_e[h][e] fp16
// [4MB        , 4MB+64KB)     : sdec  f32[16][1024]
// [4MB+64KB   , 4MB+576KB)    : part  f32[4][32768]     per-coltile partial logits
#define WS_WE16_OFF   0
#define WS_SDEC_OFF   (4u << 20)
#define WS_PART_OFF   ((4u << 20) + (64u << 10))

// Convert W_e = attn_w[:, H:3H] to fp16, layout [h][e] row-major.
__global__ void wecvt_kernel(const float* __restrict__ attn_w, f16* __restrict__ we16) {
    int idx = blockIdx.x * 256 + threadIdx.x;     // float4 index, 1024*512 total
    int h  = idx >> 9;                            // 512 float4 per row
    int e4 = idx & 511;
    const float4 v4 = *reinterpret_cast<const float4*>(attn_w + (size_t)h * 3072 + 1024 + e4 * 4);
    f16x4 hv = { (f16)v4.x, (f16)v4.y, (f16)v4.z, (f16)v4.w };
    *reinterpret_cast<f16x4*>(we16 + (size_t)h * 2048 + e4 * 4) = hv;
}

// score_dec[b][h] = attn_b[h] + sum_k v[b][k] * attn_w[h][k]   (W_v = attn_w[:, :H])
__global__ void sdec_kernel(const float* __restrict__ v,
                            const float* __restrict__ attn_w,
                            const float* __restrict__ attn_b,
                            float* __restrict__ sdec) {
    int gid  = blockIdx.x * 4 + (threadIdx.x >> 6);   // one wave per (b,h)
    int lane = threadIdx.x & 63;
    int b = gid >> 10;
    int h = gid & 1023;
    const float* vr = v + b * 1024;
    const float* wr = attn_w + (size_t)h * 3072;
    float s = 0.f;
    #pragma unroll 4
    for (int k = lane; k < 1024; k += 64) s += vr[k] * wr[k];
    #pragma unroll
    for (int m = 1; m < 64; m <<= 1) s += __shfl_xor(s, m);
    if (lane == 0) sdec[b * 1024 + h] = s + attn_b[h];
}

// Main fused kernel: per 128-row x 256-col tile, full-K GEMM (fp16 MFMA),
// epilogue: tanh(score + sdec) * vw, reduce over cols -> partial logits.
__global__ __launch_bounds__(512) void fused_gemm(
        const float* __restrict__ enc,    // [32768][2048] fp32
        const f16*  __restrict__ we16,    // [1024][2048] fp16
        const float* __restrict__ sdec,   // [16][1024]
        const float* __restrict__ vw,     // [1024]
        float* __restrict__ part)         // [4][32768]
{
    const int bid = blockIdx.x;
    const int ct  = bid & 3;      // col tile (256 cols each)
    const int rt  = bid >> 2;     // row tile (128 rows each)
    const int tid  = threadIdx.x;
    const int lane = tid & 63;
    const int w    = tid >> 6;    // 0..7
    const int wm   = w >> 2;      // 0..1  (64 rows each)
    const int wn   = w & 3;       // 0..3  (64 cols each)
    const int l15  = lane & 15;
    const int l4   = lane >> 4;

    __shared__ f16 As[128][40];   // pad to 40 halfs (80B) -> 2-way conflicts only
    __shared__ f16 Bs[256][40];
    __shared__ float red[4][128];

    const int rowbase = rt * 128;
    const int colbase = ct * 256;
    const int bidx = rowbase / LSEQ;   // BM=128 divides L -> whole tile same batch

    f32x4 acc[4][4] = {};

    for (int kk = 0; kk < KDIM; kk += 32) {
        __syncthreads();
        // stage A: 128x32 fp32 -> fp16.  1024 float4s, 2 per thread
        #pragma unroll
        for (int it = 0; it < 2; ++it) {
            int f4i = it * 512 + tid;
            int r   = f4i >> 3;      // 8 float4 per row
            int c4  = f4i & 7;
            const float4 v4 = *reinterpret_cast<const float4*>(
                enc + (size_t)(rowbase + r) * 2048 + kk + c4 * 4);
            f16x4 hv = { (f16)v4.x, (f16)v4.y, (f16)v4.z, (f16)v4.w };
            *reinterpret_cast<f16x4*>(&As[r][c4 * 4]) = hv;
        }
        // stage B: 256x32 fp16.  1024 x 16B chunks, 2 per thread
        #pragma unroll
        for (int it = 0; it < 2; ++it) {
            int ci = it * 512 + tid;
            int rr = ci >> 2;        // 4 chunks per row
            int c8 = ci & 3;
            const f16x8 v8 = *reinterpret_cast<const f16x8*>(
                we16 + (size_t)(colbase + rr) * 2048 + kk + c8 * 8);
            *reinterpret_cast<f16x8*>(&Bs[rr][c8 * 8]) = v8;
        }
        __syncthreads();

        f16x8 af[4], bf[4];
        #pragma unroll
        for (int i = 0; i < 4; ++i)
            af[i] = *reinterpret_cast<const f16x8*>(&As[wm * 64 + i * 16 + l15][l4 * 8]);
        #pragma unroll
        for (int j = 0; j < 4; ++j)
            bf[j] = *reinterpret_cast<const f16x8*>(&Bs[wn * 64 + j * 16 + l15][l4 * 8]);
        #pragma unroll
        for (int i = 0; i < 4; ++i)
            #pragma unroll
            for (int j = 0; j < 4; ++j)
                acc[i][j] = __builtin_amdgcn_mfma_f32_16x16x32_f16(af[i], bf[j], acc[i][j], 0, 0, 0);
    }

    // ---------------- epilogue ----------------
    // C/D frag layout: col = lane&15, row = (lane>>4)*4 + reg   [m89-verified]
    float sd[4], vwv[4];
    #pragma unroll
    for (int j = 0; j < 4; ++j) {
        int col = colbase + wn * 64 + j * 16 + l15;
        sd[j]  = sdec[bidx * 1024 + col];
        vwv[j] = vw[col];
    }
    float psum[4][4];
    #pragma unroll
    for (int i = 0; i < 4; ++i)
        #pragma unroll
        for (int r = 0; r < 4; ++r) psum[i][r] = 0.f;

    #pragma unroll
    for (int i = 0; i < 4; ++i)
        #pragma unroll
        for (int j = 0; j < 4; ++j)
            #pragma unroll
            for (int r = 0; r < 4; ++r)
                psum[i][r] += tanhf(acc[i][j][r] + sd[j]) * vwv[j];

    // reduce over the 16 lanes (cols) sharing l4
    #pragma unroll
    for (int i = 0; i < 4; ++i)
        #pragma unroll
        for (int r = 0; r < 4; ++r) {
            float s = psum[i][r];
            #pragma unroll
            for (int m = 1; m < 16; m <<= 1) s += __shfl_xor(s, m);
            psum[i][r] = s;
        }

    __syncthreads();   // As/Bs frag reads all done; now reuse LDS phase for red
    if (l15 == 0) {
        #pragma unroll
        for (int i = 0; i < 4; ++i)
            #pragma unroll
            for (int r = 0; r < 4; ++r)
                red[wn][wm * 64 + i * 16 + l4 * 4 + r] = psum[i][r];
    }
    __syncthreads();
    if (tid < 128) {
        float tot = red[0][tid] + red[1][tid] + red[2][tid] + red[3][tid];
        part[ct * M_TOT + rowbase + tid] = tot;   // deterministic: unique owner
    }
}

// softmax over L per batch; applies mask (==0 -> -1e10) and sums the 4 partials.
__global__ __launch_bounds__(512) void softmax_kernel(
        const float* __restrict__ part, const int* __restrict__ mask,
        float* __restrict__ out) {
    int b = blockIdx.x;
    int tid = threadIdx.x;
    int lane = tid & 63, w = tid >> 6;
    __shared__ float sred[8];

    float vals[4];
    #pragma unroll
    for (int p = 0; p < 4; ++p) {
        int row = b * LSEQ + tid + p * 512;
        float val = part[row] + part[M_TOT + row] + part[2 * M_TOT + row] + part[3 * M_TOT + row];
        vals[p] = (mask[row] == 0) ? NEG_INF_F : val;
    }
    float mx = fmaxf(fmaxf(vals[0], vals[1]), fmaxf(vals[2], vals[3]));
    #pragma unroll
    for (int m = 1; m < 64; m <<= 1) mx = fmaxf(mx, __shfl_xor(mx, m));
    if (lane == 0) sred[w] = mx;
    __syncthreads();
    float gmax = sred[0];
    #pragma unroll
    for (int i = 1; i < 8; ++i) gmax = fmaxf(gmax, sred[i]);

    float es[4]; float ssum = 0.f;
    #pragma unroll
    for (int p = 0; p < 4; ++p) { es[p] = expf(vals[p] - gmax); ssum += es[p]; }
    #pragma unroll
    for (int m = 1; m < 64; m <<= 1) ssum += __shfl_xor(ssum, m);
    __syncthreads();   // done reading sred(max)
    if (lane == 0) sred[w] = ssum;
    __syncthreads();
    float gsum = 0.f;
    #pragma unroll
    for (int i = 0; i < 8; ++i) gsum += sred[i];
    float inv = 1.f / gsum;
    #pragma unroll
    for (int p = 0; p < 4; ++p)
        out[b * LSEQ + tid + p * 512] = es[p] * inv;
}

extern "C" void kernel_launch(void* const* d_in, const int* in_sizes, int n_in,
                              void* d_out, int out_size, void* d_ws, size_t ws_size,
                              hipStream_t stream) {
    const float* enc    = (const float*)d_in[0];  // encoder_out (16,2048,2048)
    const int*   mask   = (const int*)  d_in[1];  // (16,2048)
    const float* v      = (const float*)d_in[2];  // (1,16,1024)
    const float* attn_w = (const float*)d_in[3];  // (1024,3072)
    const float* attn_b = (const float*)d_in[4];  // (1024,)
    const float* v_w    = (const float*)d_in[5];  // (1,1024)
    float* out = (float*)d_out;

    char* ws = (char*)d_ws;
    f16*   we16 = (f16*)  (ws + WS_WE16_OFF);
    float* sdec = (float*)(ws + WS_SDEC_OFF);
    float* part = (float*)(ws + WS_PART_OFF);

    hipLaunchKernelGGL(wecvt_kernel, dim3(2048), dim3(256), 0, stream, attn_w, we16);
    hipLaunchKernelGGL(sdec_kernel,  dim3(4096), dim3(256), 0, stream, v, attn_w, attn_b, sdec);
    hipLaunchKernelGGL(fused_gemm,   dim3(1024), dim3(512), 0, stream, enc, we16, sdec, v_w, part);
    hipLaunchKernelGGL(softmax_kernel, dim3(16), dim3(512), 0, stream, part, mask, out);
}

// Round 2
// 356.296 us; speedup vs baseline: 1.1433x; 1.1433x over previous
//
#include <hip/hip_runtime.h>

#define H 1024
#define LSEQ 2048
#define M_TOT 32768          // B*L
#define KDIM 2048            // 2H
#define NKT 64               // K tiles of 32
#define NCT 8                // col tiles of 128
#define NEG_INF_F (-10000000000.0f)

typedef _Float16 f16;
typedef f16 f16x4 __attribute__((ext_vector_type(4)));
typedef f16 f16x8 __attribute__((ext_vector_type(8)));
typedef float f32x4 __attribute__((ext_vector_type(4)));

// ---------------- ws layout ----------------
// [0      , 4MB)        : we16  f16[1024][2048]
// [4MB    , 4MB+64KB)   : sdec  f32[16][1024]
// [4MB+64K, +1MB)       : part  f32[8][32768]
#define WS_WE16_OFF   0
#define WS_SDEC_OFF   (4u << 20)
#define WS_PART_OFF   ((4u << 20) + (64u << 10))

// Convert W_e = attn_w[:, H:3H] to fp16, layout [h][e] row-major.
__global__ void wecvt_kernel(const float* __restrict__ attn_w, f16* __restrict__ we16) {
    int idx = blockIdx.x * 256 + threadIdx.x;     // float4 index, 1024*512 total
    int h  = idx >> 9;
    int e4 = idx & 511;
    const float4 v4 = *reinterpret_cast<const float4*>(attn_w + (size_t)h * 3072 + 1024 + e4 * 4);
    f16x4 hv = { (f16)v4.x, (f16)v4.y, (f16)v4.z, (f16)v4.w };
    *reinterpret_cast<f16x4*>(we16 + (size_t)h * 2048 + e4 * 4) = hv;
}

// score_dec[b][h] = attn_b[h] + sum_k v[b][k] * attn_w[h][k]
__global__ void sdec_kernel(const float* __restrict__ v,
                            const float* __restrict__ attn_w,
                            const float* __restrict__ attn_b,
                            float* __restrict__ sdec) {
    int gid  = blockIdx.x * 4 + (threadIdx.x >> 6);
    int lane = threadIdx.x & 63;
    int b = gid >> 10;
    int h = gid & 1023;
    const float* vr = v + b * 1024;
    const float* wr = attn_w + (size_t)h * 3072;
    float s = 0.f;
    #pragma unroll 4
    for (int k = lane; k < 1024; k += 64) s += vr[k] * wr[k];
    #pragma unroll
    for (int m = 1; m < 64; m <<= 1) s += __shfl_xor(s, m);
    if (lane == 0) sdec[b * 1024 + h] = s + attn_b[h];
}

// Main fused kernel: 128x128 tile, 4 waves, BK=32.
// A: fp32 global -> reg -> cvt fp16 -> LDS (double-buffered, write-late).
// B: fp16 global (L2-resident we16) -> reg fragments (double-buffered in regs).
__global__ __launch_bounds__(256, 3) void fused_gemm(
        const float* __restrict__ enc,    // [32768][2048] fp32
        const f16*  __restrict__ we16,    // [1024][2048] fp16
        const float* __restrict__ sdec,   // [16][1024]
        const float* __restrict__ vw,     // [1024]
        float* __restrict__ part)         // [NCT][32768]
{
    // chunked XCD remap: 2048 blocks, 8 XCDs, 256 per chunk.
    const int bid = blockIdx.x;
    const int logical = (bid & 7) * 256 + (bid >> 3);
    const int rt = logical >> 3;     // row tile (128 rows)
    const int ct = logical & 7;      // col tile (128 cols) — consecutive share A panel

    const int tid  = threadIdx.x;
    const int lane = tid & 63;
    const int w    = tid >> 6;       // 0..3
    const int wm   = w >> 1;         // 0..1 (64 rows)
    const int wn   = w & 1;          // 0..1 (64 cols)
    const int l15  = lane & 15;
    const int l4   = lane >> 4;

    __shared__ f16 As[2][128][40];   // pad 40 halfs (80B rows)
    __shared__ float red[2][128];

    const int rowbase = rt * 128;
    const int colbase = ct * 128;
    const int bidx = rowbase / LSEQ;

    // A staging: thread owns 4 float4s per K-tile: f4i = it*256+tid
    // r = f4i>>3 (8 float4 per 32-float row-chunk), c4 = f4i&7  -> coalesced
    const int ar = tid >> 3;         // base row for it=0; it adds 32 rows
    const int ac4 = tid & 7;
    const float* aptr = enc + (size_t)(rowbase)*KDIM;

    // B fragment pointer: bf[j] <- we16[(colbase + wn*64 + j*16 + l15)][kk + l4*8]
    const f16* bptr = we16 + (size_t)(colbase + wn * 64 + l15) * KDIM + l4 * 8;

    f32x4 acc[4][4] = {};
    f16x8 bfc[4];

    // ---- prologue: stage tile 0 ----
    {
        #pragma unroll
        for (int it = 0; it < 4; ++it) {
            const int r = ar + it * 32;
            const float4 v4 = *reinterpret_cast<const float4*>(aptr + (size_t)r * KDIM + ac4 * 4);
            f16x4 hv = { (f16)v4.x, (f16)v4.y, (f16)v4.z, (f16)v4.w };
            *reinterpret_cast<f16x4*>(&As[0][r][ac4 * 4]) = hv;
        }
        #pragma unroll
        for (int j = 0; j < 4; ++j)
            bfc[j] = *reinterpret_cast<const f16x8*>(bptr + (size_t)j * 16 * KDIM);
        __syncthreads();
    }

    auto iter = [&](int t, int CUR) {
        const int NXT = CUR ^ 1;
        float4 sa[4];
        f16x8 bnew[4];
        const bool pre = (t + 1 < NKT);
        const int kk2 = (t + 1) * 32;
        if (pre) {
            #pragma unroll
            for (int it = 0; it < 4; ++it) {
                const int r = ar + it * 32;
                sa[it] = *reinterpret_cast<const float4*>(aptr + (size_t)r * KDIM + kk2 + ac4 * 4);
            }
            #pragma unroll
            for (int j = 0; j < 4; ++j)
                bnew[j] = *reinterpret_cast<const f16x8*>(bptr + (size_t)j * 16 * KDIM + kk2);
        }
        // compute on As[CUR] with bfc
        f16x8 af[4];
        #pragma unroll
        for (int i = 0; i < 4; ++i)
            af[i] = *reinterpret_cast<const f16x8*>(&As[CUR][wm * 64 + i * 16 + l15][l4 * 8]);
        #pragma unroll
        for (int i = 0; i < 4; ++i)
            #pragma unroll
            for (int j = 0; j < 4; ++j)
                acc[i][j] = __builtin_amdgcn_mfma_f32_16x16x32_f16(af[i], bfc[j], acc[i][j], 0, 0, 0);
        // write-late: stage regs -> As[NXT]
        if (pre) {
            #pragma unroll
            for (int it = 0; it < 4; ++it) {
                const int r = ar + it * 32;
                f16x4 hv = { (f16)sa[it].x, (f16)sa[it].y, (f16)sa[it].z, (f16)sa[it].w };
                *reinterpret_cast<f16x4*>(&As[NXT][r][ac4 * 4]) = hv;
            }
            #pragma unroll
            for (int j = 0; j < 4; ++j) bfc[j] = bnew[j];
        }
        __syncthreads();
    };

    for (int t = 0; t < NKT; t += 2) {
        iter(t, 0);
        iter(t + 1, 1);
    }

    // ---------------- epilogue ----------------
    // C/D frag: col = lane&15, row = (lane>>4)*4 + reg
    float sd[4], vwv[4];
    #pragma unroll
    for (int j = 0; j < 4; ++j) {
        const int col = colbase + wn * 64 + j * 16 + l15;
        sd[j]  = sdec[bidx * 1024 + col];
        vwv[j] = vw[col];
    }
    float psum[4][4];
    #pragma unroll
    for (int i = 0; i < 4; ++i)
        #pragma unroll
        for (int r = 0; r < 4; ++r) psum[i][r] = 0.f;

    #pragma unroll
    for (int i = 0; i < 4; ++i)
        #pragma unroll
        for (int j = 0; j < 4; ++j)
            #pragma unroll
            for (int r = 0; r < 4; ++r)
                psum[i][r] += tanhf(acc[i][j][r] + sd[j]) * vwv[j];

    #pragma unroll
    for (int i = 0; i < 4; ++i)
        #pragma unroll
        for (int r = 0; r < 4; ++r) {
            float s = psum[i][r];
            #pragma unroll
            for (int m = 1; m < 16; m <<= 1) s += __shfl_xor(s, m);
            psum[i][r] = s;
        }

    if (l15 == 0) {
        #pragma unroll
        for (int i = 0; i < 4; ++i)
            #pragma unroll
            for (int r = 0; r < 4; ++r)
                red[wn][wm * 64 + i * 16 + l4 * 4 + r] = psum[i][r];
    }
    __syncthreads();
    if (tid < 128) {
        const float tot = red[0][tid] + red[1][tid];
        part[(size_t)ct * M_TOT + rowbase + tid] = tot;
    }
}

// softmax over L per batch; mask==0 -> -1e10; sums the NCT partials.
__global__ __launch_bounds__(512) void softmax_kernel(
        const float* __restrict__ part, const int* __restrict__ mask,
        float* __restrict__ out) {
    int b = blockIdx.x;
    int tid = threadIdx.x;
    int lane = tid & 63, w = tid >> 6;
    __shared__ float sred[8];

    float vals[4];
    #pragma unroll
    for (int p = 0; p < 4; ++p) {
        int row = b * LSEQ + tid + p * 512;
        float val = 0.f;
        #pragma unroll
        for (int q = 0; q < NCT; ++q) val += part[(size_t)q * M_TOT + row];
        vals[p] = (mask[row] == 0) ? NEG_INF_F : val;
    }
    float mx = fmaxf(fmaxf(vals[0], vals[1]), fmaxf(vals[2], vals[3]));
    #pragma unroll
    for (int m = 1; m < 64; m <<= 1) mx = fmaxf(mx, __shfl_xor(mx, m));
    if (lane == 0) sred[w] = mx;
    __syncthreads();
    float gmax = sred[0];
    #pragma unroll
    for (int i = 1; i < 8; ++i) gmax = fmaxf(gmax, sred[i]);

    float es[4]; float ssum = 0.f;
    #pragma unroll
    for (int p = 0; p < 4; ++p) { es[p] = expf(vals[p] - gmax); ssum += es[p]; }
    #pragma unroll
    for (int m = 1; m < 64; m <<= 1) ssum += __shfl_xor(ssum, m);
    __syncthreads();
    if (lane == 0) sred[w] = ssum;
    __syncthreads();
    float gsum = 0.f;
    #pragma unroll
    for (int i = 0; i < 8; ++i) gsum += sred[i];
    float inv = 1.f / gsum;
    #pragma unroll
    for (int p = 0; p < 4; ++p)
        out[b * LSEQ + tid + p * 512] = es[p] * inv;
}

extern "C" void kernel_launch(void* const* d_in, const int* in_sizes, int n_in,
                              void* d_out, int out_size, void* d_ws, size_t ws_size,
                              hipStream_t stream) {
    const float* enc    = (const float*)d_in[0];
    const int*   mask   = (const int*)  d_in[1];
    const float* v      = (const float*)d_in[2];
    const float* attn_w = (const float*)d_in[3];
    const float* attn_b = (const float*)d_in[4];
    const float* v_w    = (const float*)d_in[5];
    float* out = (float*)d_out;

    char* ws = (char*)d_ws;
    f16*   we16 = (f16*)  (ws + WS_WE16_OFF);
    float* sdec = (float*)(ws + WS_SDEC_OFF);
    float* part = (float*)(ws + WS_PART_OFF);

    hipLaunchKernelGGL(wecvt_kernel, dim3(2048), dim3(256), 0, stream, attn_w, we16);
    hipLaunchKernelGGL(sdec_kernel,  dim3(4096), dim3(256), 0, stream, v, attn_w, attn_b, sdec);
    hipLaunchKernelGGL(fused_gemm,   dim3(2048), dim3(256), 0, stream, enc, we16, sdec, v_w, part);
    hipLaunchKernelGGL(softmax_kernel, dim3(16), dim3(512), 0, stream, part, mask, out);
}

// Round 3
// 341.303 us; speedup vs baseline: 1.1936x; 1.0439x over previous
//
#include <hip/hip_runtime.h>

#define H 1024
#define LSEQ 2048
#define M_TOT 32768          // B*L
#define KDIM 2048            // 2H
#define NKT 64               // K tiles of 32
#define NCT 8                // col tiles of 128
#define NEG_INF_F (-10000000000.0f)

typedef _Float16 f16;
typedef f16 f16x4 __attribute__((ext_vector_type(4)));
typedef f16 f16x8 __attribute__((ext_vector_type(8)));
typedef float f32x4 __attribute__((ext_vector_type(4)));

// ---------------- ws layout ----------------
#define WS_WE16_OFF   0
#define WS_SDEC_OFF   (4u << 20)
#define WS_PART_OFF   ((4u << 20) + (64u << 10))

// Convert W_e = attn_w[:, H:3H] to fp16, layout [h][e] row-major.
__global__ void wecvt_kernel(const float* __restrict__ attn_w, f16* __restrict__ we16) {
    int idx = blockIdx.x * 256 + threadIdx.x;
    int h  = idx >> 9;
    int e4 = idx & 511;
    const float4 v4 = *reinterpret_cast<const float4*>(attn_w + (size_t)h * 3072 + 1024 + e4 * 4);
    f16x4 hv = { (f16)v4.x, (f16)v4.y, (f16)v4.z, (f16)v4.w };
    *reinterpret_cast<f16x4*>(we16 + (size_t)h * 2048 + e4 * 4) = hv;
}

// score_dec[b][h] = attn_b[h] + sum_k v[b][k] * attn_w[h][k]
__global__ void sdec_kernel(const float* __restrict__ v,
                            const float* __restrict__ attn_w,
                            const float* __restrict__ attn_b,
                            float* __restrict__ sdec) {
    int gid  = blockIdx.x * 4 + (threadIdx.x >> 6);
    int lane = threadIdx.x & 63;
    int b = gid >> 10;
    int h = gid & 1023;
    const float* vr = v + b * 1024;
    const float* wr = attn_w + (size_t)h * 3072;
    float s = 0.f;
    #pragma unroll 4
    for (int k = lane; k < 1024; k += 64) s += vr[k] * wr[k];
    #pragma unroll
    for (int m = 1; m < 64; m <<= 1) s += __shfl_xor(s, m);
    if (lane == 0) sdec[b * 1024 + h] = s + attn_b[h];
}

// Main fused kernel: 128x128 tile, 4 waves, BK=32.
// A: fp32 global -> reg (depth-2 prefetch) -> cvt fp16 -> LDS (b128 writes, dbuf).
// B: fp16 global (L2-resident) -> reg fragments (depth-1 reg double-buffer).
__global__ __launch_bounds__(256, 3) void fused_gemm(
        const float* __restrict__ enc,    // [32768][2048] fp32
        const f16*  __restrict__ we16,    // [1024][2048] fp16
        const float* __restrict__ sdec,   // [16][1024]
        const float* __restrict__ vw,     // [1024]
        float* __restrict__ part)         // [NCT][32768]
{
    // chunked XCD remap: 2048 blocks, 8 XCDs, 256 per chunk.
    const int bid = blockIdx.x;
    const int logical = (bid & 7) * 256 + (bid >> 3);
    const int rt = logical >> 3;     // row tile (128 rows)
    const int ct = logical & 7;      // col tile (128 cols)

    const int tid  = threadIdx.x;
    const int lane = tid & 63;
    const int w    = tid >> 6;       // 0..3
    const int wm   = w >> 1;
    const int wn   = w & 1;
    const int l15  = lane & 15;
    const int l4   = lane >> 4;

    __shared__ f16 As[2][128][40];   // 80B rows; write group=(5r+p)%8, read group=(5*l15+l4)%8 both uniform
    __shared__ float red[2][128];

    const int rowbase = rt * 128;
    const int colbase = ct * 128;
    const int bidx = rowbase / LSEQ;

    // A staging: thread owns rows {tid>>2, (tid>>2)+64}, 8 consecutive floats at col (tid&3)*8.
    const int ar = tid >> 2;
    const int ap = tid & 3;
    const float* aBase = enc + (size_t)(rowbase + ar) * KDIM + ap * 8;

    // B fragment pointer: bf[j] <- we16[(colbase + wn*64 + j*16 + l15)][kk + l4*8]
    const f16* bptr = we16 + (size_t)(colbase + wn * 64 + l15) * KDIM + l4 * 8;

    f32x4 acc[4][4] = {};
    f16x8 bfc[4];
    float4 saA[4], saB[4];

    auto loadA = [&](float4 (&sa)[4], int kk) {
        sa[0] = *reinterpret_cast<const float4*>(aBase + kk);
        sa[1] = *reinterpret_cast<const float4*>(aBase + kk + 4);
        sa[2] = *reinterpret_cast<const float4*>(aBase + kk + (size_t)64 * KDIM);
        sa[3] = *reinterpret_cast<const float4*>(aBase + kk + (size_t)64 * KDIM + 4);
    };
    auto writeA = [&](const float4 (&sa)[4], int NXT) {
        f16x8 h0 = { (f16)sa[0].x, (f16)sa[0].y, (f16)sa[0].z, (f16)sa[0].w,
                     (f16)sa[1].x, (f16)sa[1].y, (f16)sa[1].z, (f16)sa[1].w };
        f16x8 h1 = { (f16)sa[2].x, (f16)sa[2].y, (f16)sa[2].z, (f16)sa[2].w,
                     (f16)sa[3].x, (f16)sa[3].y, (f16)sa[3].z, (f16)sa[3].w };
        *reinterpret_cast<f16x8*>(&As[NXT][ar][ap * 8]) = h0;
        *reinterpret_cast<f16x8*>(&As[NXT][ar + 64][ap * 8]) = h1;
    };

    // ---- prologue ----
    loadA(saA, 0);                 // tile 0
    loadA(saB, 32);                // tile 1
    #pragma unroll
    for (int j = 0; j < 4; ++j)
        bfc[j] = *reinterpret_cast<const f16x8*>(bptr + (size_t)j * 16 * KDIM);
    writeA(saA, 0);                // waits only saA (counted vmcnt)
    __syncthreads();

    // body: compute on As[CUR]; issue A(t+2)->saNew; write A(t+1) from saOld; B dbuf.
    auto body = [&](int t, int CUR, float4 (&saNew)[4], float4 (&saOld)[4]) {
        const int NXT = CUR ^ 1;
        if (t + 2 < NKT) loadA(saNew, (t + 2) * 32);
        f16x8 bnew[4];
        if (t + 1 < NKT) {
            const int kk2 = (t + 1) * 32;
            #pragma unroll
            for (int j = 0; j < 4; ++j)
                bnew[j] = *reinterpret_cast<const f16x8*>(bptr + (size_t)j * 16 * KDIM + kk2);
        }
        f16x8 af[4];
        #pragma unroll
        for (int i = 0; i < 4; ++i)
            af[i] = *reinterpret_cast<const f16x8*>(&As[CUR][wm * 64 + i * 16 + l15][l4 * 8]);
        #pragma unroll
        for (int i = 0; i < 4; ++i)
            #pragma unroll
            for (int j = 0; j < 4; ++j)
                acc[i][j] = __builtin_amdgcn_mfma_f32_16x16x32_f16(af[i], bfc[j], acc[i][j], 0, 0, 0);
        if (t + 1 < NKT) {
            writeA(saOld, NXT);
            #pragma unroll
            for (int j = 0; j < 4; ++j) bfc[j] = bnew[j];
        }
        __syncthreads();
    };

    for (int t = 0; t < NKT; t += 2) {
        body(t,     0, saA, saB);   // consumes saB (tile t+1), issues saA (tile t+2)
        body(t + 1, 1, saB, saA);   // consumes saA (tile t+2), issues saB (tile t+3)
    }

    // ---------------- epilogue ----------------
    // C/D frag: col = lane&15, row = (lane>>4)*4 + reg
    float sd[4], vwv[4];
    #pragma unroll
    for (int j = 0; j < 4; ++j) {
        const int col = colbase + wn * 64 + j * 16 + l15;
        sd[j]  = sdec[bidx * 1024 + col];
        vwv[j] = vw[col];
    }
    float psum[4][4];
    #pragma unroll
    for (int i = 0; i < 4; ++i)
        #pragma unroll
        for (int r = 0; r < 4; ++r) psum[i][r] = 0.f;

    #pragma unroll
    for (int i = 0; i < 4; ++i)
        #pragma unroll
        for (int j = 0; j < 4; ++j)
            #pragma unroll
            for (int r = 0; r < 4; ++r)
                psum[i][r] += tanhf(acc[i][j][r] + sd[j]) * vwv[j];

    #pragma unroll
    for (int i = 0; i < 4; ++i)
        #pragma unroll
        for (int r = 0; r < 4; ++r) {
            float s = psum[i][r];
            #pragma unroll
            for (int m = 1; m < 16; m <<= 1) s += __shfl_xor(s, m);
            psum[i][r] = s;
        }

    if (l15 == 0) {
        #pragma unroll
        for (int i = 0; i < 4; ++i)
            #pragma unroll
            for (int r = 0; r < 4; ++r)
                red[wn][wm * 64 + i * 16 + l4 * 4 + r] = psum[i][r];
    }
    __syncthreads();
    if (tid < 128) {
        const float tot = red[0][tid] + red[1][tid];
        part[(size_t)ct * M_TOT + rowbase + tid] = tot;
    }
}

// softmax over L per batch; mask==0 -> -1e10; sums the NCT partials.
__global__ __launch_bounds__(512) void softmax_kernel(
        const float* __restrict__ part, const int* __restrict__ mask,
        float* __restrict__ out) {
    int b = blockIdx.x;
    int tid = threadIdx.x;
    int lane = tid & 63, w = tid >> 6;
    __shared__ float sred[8];

    float vals[4];
    #pragma unroll
    for (int p = 0; p < 4; ++p) {
        int row = b * LSEQ + tid + p * 512;
        float val = 0.f;
        #pragma unroll
        for (int q = 0; q < NCT; ++q) val += part[(size_t)q * M_TOT + row];
        vals[p] = (mask[row] == 0) ? NEG_INF_F : val;
    }
    float mx = fmaxf(fmaxf(vals[0], vals[1]), fmaxf(vals[2], vals[3]));
    #pragma unroll
    for (int m = 1; m < 64; m <<= 1) mx = fmaxf(mx, __shfl_xor(mx, m));
    if (lane == 0) sred[w] = mx;
    __syncthreads();
    float gmax = sred[0];
    #pragma unroll
    for (int i = 1; i < 8; ++i) gmax = fmaxf(gmax, sred[i]);

    float es[4]; float ssum = 0.f;
    #pragma unroll
    for (int p = 0; p < 4; ++p) { es[p] = expf(vals[p] - gmax); ssum += es[p]; }
    #pragma unroll
    for (int m = 1; m < 64; m <<= 1) ssum += __shfl_xor(ssum, m);
    __syncthreads();
    if (lane == 0) sred[w] = ssum;
    __syncthreads();
    float gsum = 0.f;
    #pragma unroll
    for (int i = 0; i < 8; ++i) gsum += sred[i];
    float inv = 1.f / gsum;
    #pragma unroll
    for (int p = 0; p < 4; ++p)
        out[b * LSEQ + tid + p * 512] = es[p] * inv;
}

extern "C" void kernel_launch(void* const* d_in, const int* in_sizes, int n_in,
                              void* d_out, int out_size, void* d_ws, size_t ws_size,
                              hipStream_t stream) {
    const float* enc    = (const float*)d_in[0];
    const int*   mask   = (const int*)  d_in[1];
    const float* v      = (const float*)d_in[2];
    const float* attn_w = (const float*)d_in[3];
    const float* attn_b = (const float*)d_in[4];
    const float* v_w    = (const float*)d_in[5];
    float* out = (float*)d_out;

    char* ws = (char*)d_ws;
    f16*   we16 = (f16*)  (ws + WS_WE16_OFF);
    float* sdec = (float*)(ws + WS_SDEC_OFF);
    float* part = (float*)(ws + WS_PART_OFF);

    hipLaunchKernelGGL(wecvt_kernel, dim3(2048), dim3(256), 0, stream, attn_w, we16);
    hipLaunchKernelGGL(sdec_kernel,  dim3(4096), dim3(256), 0, stream, v, attn_w, attn_b, sdec);
    hipLaunchKernelGGL(fused_gemm,   dim3(2048), dim3(256), 0, stream, enc, we16, sdec, v_w, part);
    hipLaunchKernelGGL(softmax_kernel, dim3(16), dim3(512), 0, stream, part, mask, out);
}